// Round 1
// baseline (292.593 us; speedup 1.0000x reference)
//
#include <hip/hip_runtime.h>
#include <math.h>

// Problem constants
#define HH 512
#define WW 512
#define NB 64
#define CXY 56          // crop offset of Xc in x
#define TOFF 66         // crop offset of tmpl in template (MS+C = 10+56)
#define TN 380          // template side
#define XN 400          // cropped image side
#define NL 21           // number of lags per dim (XN-TN+1)
#define N_T 144400.0f   // TN*TN
#define EPSF 1e-8f

// d_ws float offsets
#define TPART_S   0                    // 380
#define TPART_S2  384                  // 380
#define TSTATS    768                  // [0]=mu_t [1]=t_var
#define ROWSUM    1024                 // 64*400*21 = 537600
#define ROWSUMSQ  (ROWSUM + 537600)
#define LOCALSUM  (ROWSUMSQ + 537600)  // 64*441
#define LOCALSQ   (LOCALSUM + 28224)
#define CCPART    (LOCALSQ + 28224)    // 64*16*441 = 451584
#define SHIFTS    (CCPART + 451584)    // 128

// ---------------- K0a: per-template-row partial sums ----------------
__global__ __launch_bounds__(128) void k_tstats1(const float* __restrict__ tpl,
                                                 float* __restrict__ ws) {
    int u = blockIdx.x;            // 0..379
    int l = threadIdx.x;           // 128
    const float* row = tpl + (TOFF + u) * WW + TOFF;
    float s = 0.f, s2 = 0.f;
    for (int v = l; v < TN; v += 128) { float t = row[v]; s += t; s2 += t * t; }
    for (int off = 32; off; off >>= 1) { s += __shfl_down(s, off); s2 += __shfl_down(s2, off); }
    __shared__ float rs[2], rs2[2];
    int wid = l >> 6;
    if ((l & 63) == 0) { rs[wid] = s; rs2[wid] = s2; }
    __syncthreads();
    if (l == 0) { ws[TPART_S + u] = rs[0] + rs[1]; ws[TPART_S2 + u] = rs2[0] + rs2[1]; }
}

// ---------------- K0b: finalize template stats ----------------
__global__ __launch_bounds__(512) void k_tstats2(float* __restrict__ ws) {
    int l = threadIdx.x;           // 512
    float s  = (l < TN) ? ws[TPART_S + l]  : 0.f;
    float s2 = (l < TN) ? ws[TPART_S2 + l] : 0.f;
    for (int off = 32; off; off >>= 1) { s += __shfl_down(s, off); s2 += __shfl_down(s2, off); }
    __shared__ float rs[8], rs2[8];
    int wid = l >> 6;
    if ((l & 63) == 0) { rs[wid] = s; rs2[wid] = s2; }
    __syncthreads();
    if (l == 0) {
        float S = 0.f, S2 = 0.f;
        for (int k = 0; k < 8; ++k) { S += rs[k]; S2 += rs2[k]; }
        float mu = S / N_T;
        ws[TSTATS] = mu;
        ws[TSTATS + 1] = S2 - S * mu + EPSF;   // sum((T-mu)^2) + EPS
    }
}

// ---------------- K1: per-row 380-wide sliding window sums ----------------
__global__ __launch_bounds__(256) void k_rowsum(const float* __restrict__ x,
                                                float* __restrict__ ws) {
    __shared__ float sm[4][XN];
    int wid = threadIdx.x >> 6, lane = threadIdx.x & 63;
    int row = blockIdx.x * 4 + wid;        // 0..25599
    int b = row / XN, p = row % XN;
    const float* xr = x + ((size_t)b * HH + (CXY + p)) * WW + CXY;
    float s = 0.f, s2 = 0.f;
    for (int v = lane; v < XN; v += 64) {
        float t = xr[v];
        sm[wid][v] = t;
        if (v < TN) { s += t; s2 += t * t; }
    }
    for (int off = 32; off; off >>= 1) { s += __shfl_down(s, off); s2 += __shfl_down(s2, off); }
    __syncthreads();
    if (lane == 0) {
        float* rs  = ws + ROWSUM   + (size_t)row * NL;
        float* rq  = ws + ROWSUMSQ + (size_t)row * NL;
        float w = s, w2 = s2;
        rs[0] = w; rq[0] = w2;
        for (int j = 1; j < NL; ++j) {
            float a = sm[wid][j - 1], bv = sm[wid][j + TN - 1];
            w  += bv - a;
            w2 += bv * bv - a * a;
            rs[j] = w; rq[j] = w2;
        }
    }
}

// ---------------- K2: vertical 380-tall sums -> localsum / localsum_sq ----------------
__global__ __launch_bounds__(512) void k_vert(float* __restrict__ ws) {
    int b = blockIdx.x, t = threadIdx.x;
    __shared__ float sm[XN * NL];   // 8400 floats = 33.6KB
    for (int k = t; k < XN * NL; k += 512) sm[k] = ws[ROWSUM + (size_t)b * (XN * NL) + k];
    __syncthreads();
    if (t < NL * NL) {
        float s = 0.f;
        for (int p = 0; p < TN; ++p) s += sm[t + p * NL];
        ws[LOCALSUM + b * (NL * NL) + t] = s;
    }
    __syncthreads();
    for (int k = t; k < XN * NL; k += 512) sm[k] = ws[ROWSUMSQ + (size_t)b * (XN * NL) + k];
    __syncthreads();
    if (t < NL * NL) {
        float s = 0.f;
        for (int p = 0; p < TN; ++p) s += sm[t + p * NL];
        ws[LOCALSQ + b * (NL * NL) + t] = s;
    }
}

// ---------------- K3: cross-correlation with zero-mean template ----------------
#define RPB 25           // X rows per block (16 blocks/batch)
#define TSTRIDE 388      // padded template row stride in LDS
__global__ __launch_bounds__(256) void k_cc(const float* __restrict__ x,
                                            const float* __restrict__ tpl,
                                            float* __restrict__ ws) {
    __shared__ __align__(16) float sT[21 * TSTRIDE];  // ring of 21 template rows
    __shared__ __align__(16) float sX[408];           // current X row (+zero pad)
    const int b = blockIdx.x, s = blockIdx.y;
    const int p0 = s * RPB;
    const int tid = threadIdx.x;
    const float mu = ws[TSTATS];

    // initial ring: rows u in [p0-20, p0-1]
    for (int r = 0; r < 20; ++r) {
        int u = p0 - 20 + r;
        int slot = ((u % 21) + 21) % 21;
        float* dst = sT + slot * TSTRIDE;
        if (u >= 0) {
            const float* src = tpl + (TOFF + u) * WW + TOFF;
            for (int w = tid; w < TSTRIDE; w += 256) dst[w] = (w < TN) ? (src[w] - mu) : 0.f;
        } else {
            for (int w = tid; w < TSTRIDE; w += 256) dst[w] = 0.f;
        }
    }

    const int i = tid % 21, c = tid / 21;   // lag-row, v-chunk; active if tid<252
    const bool act = (tid < 252);
    float acc[NL];
#pragma unroll
    for (int j = 0; j < NL; ++j) acc[j] = 0.f;

    for (int p = p0; p < p0 + RPB; ++p) {
        __syncthreads();   // WAR: previous compute done before restaging
        if (p <= TN - 1) { // stage template row u=p into slot p%21
            int slot = p % 21;
            const float* src = tpl + (TOFF + p) * WW + TOFF;
            float* dst = sT + slot * TSTRIDE;
            for (int w = tid; w < TSTRIDE; w += 256) dst[w] = (w < TN) ? (src[w] - mu) : 0.f;
        }
        {   // stage X row p
            const float* xr = x + ((size_t)b * HH + (CXY + p)) * WW + CXY;
            for (int w = tid; w < 408; w += 256) sX[w] = (w < XN) ? xr[w] : 0.f;
        }
        __syncthreads();
        int u = p - i;
        if (act && u <= TN - 1) {           // u<0 slots are zero-filled: contribute 0
            int slot = ((u % 21) + 21) % 21;
            const float* tr = sT + slot * TSTRIDE + c * 32;
            const float* xr = sX + c * 32;
            float wreg[52];
#pragma unroll
            for (int k = 0; k < 13; ++k) {
                float4 v = *reinterpret_cast<const float4*>(xr + 4 * k);
                wreg[4 * k]     = v.x; wreg[4 * k + 1] = v.y;
                wreg[4 * k + 2] = v.z; wreg[4 * k + 3] = v.w;
            }
#pragma unroll
            for (int g = 0; g < 8; ++g) {
                float4 t4 = *reinterpret_cast<const float4*>(tr + 4 * g);
#pragma unroll
                for (int dv = 0; dv < 4; ++dv) {
                    float tv = (dv == 0) ? t4.x : (dv == 1) ? t4.y : (dv == 2) ? t4.z : t4.w;
                    int v = 4 * g + dv;
#pragma unroll
                    for (int j = 0; j < NL; ++j)
                        acc[j] = fmaf(wreg[v + j], tv, acc[j]);
                }
            }
        }
    }

    __syncthreads();
    float* red = sT;   // reuse LDS: 441*12 floats
    if (act) {
#pragma unroll
        for (int j = 0; j < NL; ++j) red[(i * NL + j) * 12 + c] = acc[j];
    }
    __syncthreads();
    if (tid < NL * NL) {
        float ssum = 0.f;
#pragma unroll
        for (int cc2 = 0; cc2 < 12; ++cc2) ssum += red[tid * 12 + cc2];
        ws[CCPART + ((size_t)(b * 16 + s)) * (NL * NL) + tid] = ssum;
    }
}

// ---------------- K4: NCC, argmax (first-index ties), subpixel shifts ----------------
__global__ __launch_bounds__(512) void k_ncc(float* __restrict__ ws) {
    int b = blockIdx.x, t = threadIdx.x;
    __shared__ float nccs[NL * NL];
    __shared__ float vbuf[512];
    __shared__ int   ibuf[512];
    float val = -1e30f;
    if (t < NL * NL) {
        float num = 0.f;
        for (int sl = 0; sl < 16; ++sl)
            num += ws[CCPART + ((size_t)(b * 16 + sl)) * (NL * NL) + t];
        float ls  = ws[LOCALSUM + b * (NL * NL) + t];
        float lsq = ws[LOCALSQ  + b * (NL * NL) + t];
        float ivar = lsq - ls * ls * (1.0f / N_T) + EPSF;
        if (ivar < 0.f) ivar = 0.f;
        float den = sqrtf(ws[TSTATS + 1] * ivar);
        float ncc = num / den;
        if (ncc != ncc) ncc = 0.f;
        nccs[t] = ncc;
        val = ncc;
    }
    vbuf[t] = val; ibuf[t] = t;
    __syncthreads();
    for (int off = 256; off; off >>= 1) {
        if (t < off) {
            float v1 = vbuf[t], v2 = vbuf[t + off];
            int   i1 = ibuf[t], i2 = ibuf[t + off];
            if (v2 > v1 || (v2 == v1 && i2 < i1)) { vbuf[t] = v2; ibuf[t] = i2; }
        }
        __syncthreads();
    }
    if (t == 0) {
        int am = ibuf[0];
        int sx = am / NL, sy = am % NL;
        auto G = [&](int dx, int dy) -> float {
            int rx = min(max(sx + dx, 0), NL - 1);
            int ry = min(max(sy + dy, 0), NL - 1);
            return logf(nccs[rx * NL + ry]);
        };
        float l00 = G(0, 0);
        float lxm = G(-1, 0), lxp = G(1, 0);
        float lym = G(0, -1), lyp = G(0, 1);
        float shx = -(float)(sx - 10) - (lxm - lxp) / (2.f * lxm - 4.f * l00 + 2.f * lxp);
        float shy = -(float)(sy - 10) - (lym - lyp) / (2.f * lym - 4.f * l00 + 2.f * lyp);
        ws[SHIFTS + 2 * b]     = shx;
        ws[SHIFTS + 2 * b + 1] = shy;
    }
}

// ---------------- K5: bilinear warp + transposed write ----------------
__global__ __launch_bounds__(256) void k_warp(const float* __restrict__ x,
                                              const float* __restrict__ ws,
                                              float* __restrict__ out) {
    int b = blockIdx.z;
    int r = blockIdx.x * 64 + threadIdx.x;
    int cbase = blockIdx.y * 16 + threadIdx.y;
    float dy = ws[SHIFTS + 2 * b], dx = ws[SHIFTS + 2 * b + 1];
    const float* img = x + (size_t)b * (HH * WW);
    float rr = (float)r - dy;
    float r0f = floorf(rr);
    float wr = rr - r0f;
    int r0 = (int)r0f;
    for (int cc = 0; cc < 4; ++cc) {
        int c = cbase + cc * 4;
        float cf = (float)c - dx;
        float c0f = floorf(cf);
        float wc = cf - c0f;
        int c0 = (int)c0f;
        auto samp = [&](int ri, int ci) -> float {
            bool valid = (ri >= 0) & (ri < HH) & (ci >= 0) & (ci < WW);
            int rcl = min(max(ri, 0), HH - 1), ccl = min(max(ci, 0), WW - 1);
            float v = img[rcl * WW + ccl];
            return valid ? v : 0.f;
        };
        float v00 = samp(r0, c0),     v01 = samp(r0, c0 + 1);
        float v10 = samp(r0 + 1, c0), v11 = samp(r0 + 1, c0 + 1);
        float o = v00 * (1.f - wr) * (1.f - wc) + v01 * (1.f - wr) * wc
                + v10 * wr * (1.f - wc)         + v11 * wr * wc;
        out[(size_t)b * (HH * WW) + (size_t)c * HH + r] = o;
    }
}

extern "C" void kernel_launch(void* const* d_in, const int* in_sizes, int n_in,
                              void* d_out, int out_size, void* d_ws, size_t ws_size,
                              hipStream_t stream) {
    const float* x   = (const float*)d_in[0];
    const float* tpl = (const float*)d_in[1];
    float* out = (float*)d_out;
    float* ws  = (float*)d_ws;

    k_tstats1<<<TN, 128, 0, stream>>>(tpl, ws);
    k_tstats2<<<1, 512, 0, stream>>>(ws);
    k_rowsum<<<(NB * XN) / 4, 256, 0, stream>>>(x, ws);
    k_vert<<<NB, 512, 0, stream>>>(ws);
    k_cc<<<dim3(NB, 16), 256, 0, stream>>>(x, tpl, ws);
    k_ncc<<<NB, 512, 0, stream>>>(ws);
    k_warp<<<dim3(8, 32, NB), dim3(64, 4), 0, stream>>>(x, ws, out);
}

// Round 2
// 192.968 us; speedup vs baseline: 1.5163x; 1.5163x over previous
//
#include <hip/hip_runtime.h>
#include <math.h>

// Problem constants
#define HH 512
#define WW 512
#define NB 64
#define CXY 56          // crop offset of Xc in x
#define TOFF 66         // crop offset of tmpl in template (MS+C = 10+56)
#define TN 380          // template side
#define XN 400          // cropped image side
#define NL 21           // number of lags per dim (XN-TN+1)
#define N_T 144400.0f   // TN*TN
#define EPSF 1e-8f

// d_ws float offsets
#define TPART_S   0                    // 380
#define TPART_S2  384                  // 380
#define TSTATS    768                  // [0]=mu_t [1]=t_var
#define ROWSUM    1024                 // 64*400*21 = 537600
#define ROWSUMSQ  (ROWSUM + 537600)
#define LOCALSUM  (ROWSUMSQ + 537600)  // 64*441
#define LOCALSQ   (LOCALSUM + 28224)
#define CCPART    (LOCALSQ + 28224)    // 64*16*441 = 451584
#define SHIFTS    (CCPART + 451584)    // 128

// ---------------- K0a: per-template-row partial sums ----------------
__global__ __launch_bounds__(128) void k_tstats1(const float* __restrict__ tpl,
                                                 float* __restrict__ ws) {
    int u = blockIdx.x;            // 0..379
    int l = threadIdx.x;           // 128
    const float* row = tpl + (TOFF + u) * WW + TOFF;
    float s = 0.f, s2 = 0.f;
    for (int v = l; v < TN; v += 128) { float t = row[v]; s += t; s2 += t * t; }
    for (int off = 32; off; off >>= 1) { s += __shfl_down(s, off); s2 += __shfl_down(s2, off); }
    __shared__ float rs[2], rs2[2];
    int wid = l >> 6;
    if ((l & 63) == 0) { rs[wid] = s; rs2[wid] = s2; }
    __syncthreads();
    if (l == 0) { ws[TPART_S + u] = rs[0] + rs[1]; ws[TPART_S2 + u] = rs2[0] + rs2[1]; }
}

// ---------------- K0b: finalize template stats ----------------
__global__ __launch_bounds__(512) void k_tstats2(float* __restrict__ ws) {
    int l = threadIdx.x;           // 512
    float s  = (l < TN) ? ws[TPART_S + l]  : 0.f;
    float s2 = (l < TN) ? ws[TPART_S2 + l] : 0.f;
    for (int off = 32; off; off >>= 1) { s += __shfl_down(s, off); s2 += __shfl_down(s2, off); }
    __shared__ float rs[8], rs2[8];
    int wid = l >> 6;
    if ((l & 63) == 0) { rs[wid] = s; rs2[wid] = s2; }
    __syncthreads();
    if (l == 0) {
        float S = 0.f, S2 = 0.f;
        for (int k = 0; k < 8; ++k) { S += rs[k]; S2 += rs2[k]; }
        float mu = S / N_T;
        ws[TSTATS] = mu;
        ws[TSTATS + 1] = S2 - S * mu + EPSF;   // sum((T-mu)^2) + EPS
    }
}

// ---------------- K1: per-row 380-wide sliding window sums ----------------
__global__ __launch_bounds__(256) void k_rowsum(const float* __restrict__ x,
                                                float* __restrict__ ws) {
    __shared__ float sm[4][XN];
    int wid = threadIdx.x >> 6, lane = threadIdx.x & 63;
    int row = blockIdx.x * 4 + wid;        // 0..25599
    int b = row / XN, p = row % XN;
    const float* xr = x + ((size_t)b * HH + (CXY + p)) * WW + CXY;
    float s = 0.f, s2 = 0.f;
    for (int v = lane; v < XN; v += 64) {
        float t = xr[v];
        sm[wid][v] = t;
        if (v < TN) { s += t; s2 += t * t; }
    }
    for (int off = 32; off; off >>= 1) { s += __shfl_down(s, off); s2 += __shfl_down(s2, off); }
    __syncthreads();
    if (lane == 0) {
        float* rs  = ws + ROWSUM   + (size_t)row * NL;
        float* rq  = ws + ROWSUMSQ + (size_t)row * NL;
        float w = s, w2 = s2;
        rs[0] = w; rq[0] = w2;
        for (int j = 1; j < NL; ++j) {
            float a = sm[wid][j - 1], bv = sm[wid][j + TN - 1];
            w  += bv - a;
            w2 += bv * bv - a * a;
            rs[j] = w; rq[j] = w2;
        }
    }
}

// ---------------- K2: vertical 380-tall sums -> localsum / localsum_sq ----------------
__global__ __launch_bounds__(512) void k_vert(float* __restrict__ ws) {
    int b = blockIdx.x, t = threadIdx.x;
    __shared__ float sm[XN * NL];   // 8400 floats = 33.6KB
    for (int k = t; k < XN * NL; k += 512) sm[k] = ws[ROWSUM + (size_t)b * (XN * NL) + k];
    __syncthreads();
    if (t < NL * NL) {
        float s = 0.f;
        for (int p = 0; p < TN; ++p) s += sm[t + p * NL];
        ws[LOCALSUM + b * (NL * NL) + t] = s;
    }
    __syncthreads();
    for (int k = t; k < XN * NL; k += 512) sm[k] = ws[ROWSUMSQ + (size_t)b * (XN * NL) + k];
    __syncthreads();
    if (t < NL * NL) {
        float s = 0.f;
        for (int p = 0; p < TN; ++p) s += sm[t + p * NL];
        ws[LOCALSQ + b * (NL * NL) + t] = s;
    }
}

// ---------------- K3: cross-correlation with zero-mean template ----------------
// Software-pipelined: prefetch next X/T row into regs; pre-compute barrier is a
// raw s_barrier (lgkmcnt only) so prefetch vmem stays in flight across it.
#define RPB 25           // X rows per block (16 blocks/batch)
#define TSTRIDE 388      // padded template row stride in LDS
__global__ __launch_bounds__(256) void k_cc(const float* __restrict__ x,
                                            const float* __restrict__ tpl,
                                            float* __restrict__ ws) {
    __shared__ __align__(16) float sT[21 * TSTRIDE];  // ring of 21 template rows
    __shared__ __align__(16) float sX[408];           // current X row (+zero pad)
    const int b = blockIdx.x, s = blockIdx.y;
    const int p0 = s * RPB;
    const int tid = threadIdx.x;
    const float mu = ws[TSTATS];

    // initial ring: rows u in [p0-20, p0-1]
    for (int r = 0; r < 20; ++r) {
        int u = p0 - 20 + r;
        int slot = ((u % 21) + 21) % 21;
        float* dst = sT + slot * TSTRIDE;
        if (u >= 0) {
            const float* src = tpl + (TOFF + u) * WW + TOFF;
            for (int w = tid; w < TSTRIDE; w += 256) dst[w] = (w < TN) ? (src[w] - mu) : 0.f;
        } else {
            for (int w = tid; w < TSTRIDE; w += 256) dst[w] = 0.f;
        }
    }

    const int i = tid % 21, c = tid / 21;   // lag-row, v-chunk; active if tid<252
    const bool act = (tid < 252);
    float acc[NL];
#pragma unroll
    for (int j = 0; j < NL; ++j) acc[j] = 0.f;

    // prefetch row p0 (raw values; mask/subtract-mu applied at LDS-write time)
    float tp0 = 0.f, tp1 = 0.f, xp0 = 0.f, xp1 = 0.f;
    {
        if (p0 < TN) {
            const float* src = tpl + (TOFF + p0) * WW + TOFF;
            tp0 = src[tid]; tp1 = src[tid + 256];    // in-bounds: TOFF+387 < 512
        }
        const float* xr = x + ((size_t)b * HH + (CXY + p0)) * WW + CXY;
        xp0 = xr[tid]; xp1 = xr[tid + 256];          // in-bounds: CXY+407 < 512
    }

    for (int p = p0; p < p0 + RPB; ++p) {
        __syncthreads();   // WAR: previous compute done before restaging
        if (p <= TN - 1) { // stage template row u=p into slot p%21
            float* dst = sT + (p % 21) * TSTRIDE;
            dst[tid] = tp0 - mu;                               // tid<256<380 always valid
            if (tid + 256 < TSTRIDE) dst[tid + 256] = (tid + 256 < TN) ? (tp1 - mu) : 0.f;
        }
        {   // stage X row p
            sX[tid] = (tid < XN) ? xp0 : 0.f;                  // tid<256<400 always valid
            if (tid + 256 < 408) sX[tid + 256] = (tid + 256 < XN) ? xp1 : 0.f;
        }
        // prefetch row p+1 (loads overlap the compute below; not drained at barrier)
        {
            int pn = p + 1;
            if (pn < TN) {
                const float* src = tpl + (TOFF + pn) * WW + TOFF;
                tp0 = src[tid]; tp1 = src[tid + 256];
            }
            if (pn < XN) {
                const float* xr = x + ((size_t)b * HH + (CXY + pn)) * WW + CXY;
                xp0 = xr[tid]; xp1 = xr[tid + 256];
            }
        }
        // raw barrier: waits LDS writes (lgkmcnt) but leaves prefetch vmem in flight
        asm volatile("s_waitcnt lgkmcnt(0)\n\ts_barrier" ::: "memory");

        int u = p - i;
        if (act && u <= TN - 1) {           // u<0 slots are zero-filled: contribute 0
            int slot = ((u % 21) + 21) % 21;
            const float* tr = sT + slot * TSTRIDE + c * 32;
            const float* xr = sX + c * 32;
            float wreg[52];
#pragma unroll
            for (int k = 0; k < 13; ++k) {
                float4 v = *reinterpret_cast<const float4*>(xr + 4 * k);
                wreg[4 * k]     = v.x; wreg[4 * k + 1] = v.y;
                wreg[4 * k + 2] = v.z; wreg[4 * k + 3] = v.w;
            }
#pragma unroll
            for (int g = 0; g < 8; ++g) {
                float4 t4 = *reinterpret_cast<const float4*>(tr + 4 * g);
#pragma unroll
                for (int dv = 0; dv < 4; ++dv) {
                    float tv = (dv == 0) ? t4.x : (dv == 1) ? t4.y : (dv == 2) ? t4.z : t4.w;
                    int v = 4 * g + dv;
#pragma unroll
                    for (int j = 0; j < NL; ++j)
                        acc[j] = fmaf(wreg[v + j], tv, acc[j]);
                }
            }
        }
    }

    __syncthreads();
    float* red = sT;   // reuse LDS: 441*12 floats
    if (act) {
#pragma unroll
        for (int j = 0; j < NL; ++j) red[(i * NL + j) * 12 + c] = acc[j];
    }
    __syncthreads();
    if (tid < NL * NL) {
        float ssum = 0.f;
#pragma unroll
        for (int cc2 = 0; cc2 < 12; ++cc2) ssum += red[tid * 12 + cc2];
        ws[CCPART + ((size_t)(b * 16 + s)) * (NL * NL) + tid] = ssum;
    }
}

// ---------------- K4: NCC, argmax (first-index ties), subpixel shifts ----------------
__global__ __launch_bounds__(512) void k_ncc(float* __restrict__ ws) {
    int b = blockIdx.x, t = threadIdx.x;
    __shared__ float nccs[NL * NL];
    __shared__ float vbuf[512];
    __shared__ int   ibuf[512];
    float val = -1e30f;
    if (t < NL * NL) {
        float num = 0.f;
        for (int sl = 0; sl < 16; ++sl)
            num += ws[CCPART + ((size_t)(b * 16 + sl)) * (NL * NL) + t];
        float ls  = ws[LOCALSUM + b * (NL * NL) + t];
        float lsq = ws[LOCALSQ  + b * (NL * NL) + t];
        float ivar = lsq - ls * ls * (1.0f / N_T) + EPSF;
        if (ivar < 0.f) ivar = 0.f;
        float den = sqrtf(ws[TSTATS + 1] * ivar);
        float ncc = num / den;
        if (ncc != ncc) ncc = 0.f;
        nccs[t] = ncc;
        val = ncc;
    }
    vbuf[t] = val; ibuf[t] = t;
    __syncthreads();
    for (int off = 256; off; off >>= 1) {
        if (t < off) {
            float v1 = vbuf[t], v2 = vbuf[t + off];
            int   i1 = ibuf[t], i2 = ibuf[t + off];
            if (v2 > v1 || (v2 == v1 && i2 < i1)) { vbuf[t] = v2; ibuf[t] = i2; }
        }
        __syncthreads();
    }
    if (t == 0) {
        int am = ibuf[0];
        int sx = am / NL, sy = am % NL;
        auto G = [&](int dx, int dy) -> float {
            int rx = min(max(sx + dx, 0), NL - 1);
            int ry = min(max(sy + dy, 0), NL - 1);
            return logf(nccs[rx * NL + ry]);
        };
        float l00 = G(0, 0);
        float lxm = G(-1, 0), lxp = G(1, 0);
        float lym = G(0, -1), lyp = G(0, 1);
        float shx = -(float)(sx - 10) - (lxm - lxp) / (2.f * lxm - 4.f * l00 + 2.f * lxp);
        float shy = -(float)(sy - 10) - (lym - lyp) / (2.f * lym - 4.f * l00 + 2.f * lyp);
        ws[SHIFTS + 2 * b]     = shx;
        ws[SHIFTS + 2 * b + 1] = shy;
    }
}

// ---------------- K5: bilinear warp, LDS-tiled (weights are const per batch) ----------------
// out(b, c*H + r) = bilinear(img, r - dy, c - dx); since r,R integers:
// floor(r-dy) = rlo + (r-R) exactly, so wr/wc are block-constant.
__global__ __launch_bounds__(256) void k_warp(const float* __restrict__ x,
                                              const float* __restrict__ ws,
                                              float* __restrict__ out) {
    const int b = blockIdx.z;
    const int R = blockIdx.x * 64;     // output row tile
    const int C = blockIdx.y * 64;     // output col tile
    const float dy = ws[SHIFTS + 2 * b], dx = ws[SHIFTS + 2 * b + 1];
    const int rlo = (int)floorf((float)R - dy);
    const int clo = (int)floorf((float)C - dx);
    const float wr = ((float)R - dy) - (float)rlo;
    const float wc = ((float)C - dx) - (float)clo;
    __shared__ float sm[66][67];       // 66x66 staged tile, stride 67 (2-way free)
    const float* img = x + (size_t)b * (HH * WW);

    for (int k = threadIdx.x; k < 66 * 66; k += 256) {
        int kr = k / 66, kc = k - kr * 66;
        int ri = min(max(rlo + kr, 0), HH - 1);
        int ci = min(max(clo + kc, 0), WW - 1);
        sm[kr][kc] = img[ri * WW + ci];
    }
    __syncthreads();

    const int dr = threadIdx.x & 63;
    const int cq = threadIdx.x >> 6;     // 0..3
    const int r  = R + dr;
    const int r0 = rlo + dr;
    const float w00 = (1.f - wr) * (1.f - wc), w01 = (1.f - wr) * wc;
    const float w10 = wr * (1.f - wc),         w11 = wr * wc;
    const bool vr0 = (r0 >= 0) & (r0 < HH);
    const bool vr1 = (r0 + 1 >= 0) & (r0 + 1 < HH);
#pragma unroll
    for (int ci = 0; ci < 16; ++ci) {
        int dc = cq * 16 + ci;
        int c  = C + dc;
        int c0 = clo + dc;
        bool vc0 = (c0 >= 0) & (c0 < WW);
        bool vc1 = (c0 + 1 >= 0) & (c0 + 1 < WW);
        float v00 = (vr0 & vc0) ? sm[dr][dc]         : 0.f;
        float v01 = (vr0 & vc1) ? sm[dr][dc + 1]     : 0.f;
        float v10 = (vr1 & vc0) ? sm[dr + 1][dc]     : 0.f;
        float v11 = (vr1 & vc1) ? sm[dr + 1][dc + 1] : 0.f;
        float o = v00 * w00 + v01 * w01 + v10 * w10 + v11 * w11;
        out[(size_t)b * (HH * WW) + (size_t)c * HH + r] = o;
    }
}

extern "C" void kernel_launch(void* const* d_in, const int* in_sizes, int n_in,
                              void* d_out, int out_size, void* d_ws, size_t ws_size,
                              hipStream_t stream) {
    const float* x   = (const float*)d_in[0];
    const float* tpl = (const float*)d_in[1];
    float* out = (float*)d_out;
    float* ws  = (float*)d_ws;

    k_tstats1<<<TN, 128, 0, stream>>>(tpl, ws);
    k_tstats2<<<1, 512, 0, stream>>>(ws);
    k_rowsum<<<(NB * XN) / 4, 256, 0, stream>>>(x, ws);
    k_vert<<<NB, 512, 0, stream>>>(ws);
    k_cc<<<dim3(NB, 16), 256, 0, stream>>>(x, tpl, ws);
    k_ncc<<<NB, 512, 0, stream>>>(ws);
    k_warp<<<dim3(8, 8, NB), dim3(256), 0, stream>>>(x, ws, out);
}